// Round 1
// baseline (72521.436 us; speedup 1.0000x reference)
//
#include <hip/hip_runtime.h>
#include <math.h>

#define NBLK 256
#define NTHR 512
#define Bz 128
#define Sz 1024
#define Ez 256
#define Hz 512
#define K0z 768
#define K1z 1024
#define KC 64
#define APAD 132
#define HB (Hz*Bz)

__device__ __forceinline__ float sigm_(float x){ return 1.0f/(1.0f + __expf(-x)); }
__device__ __forceinline__ float tanh_(float x){
  float e = __expf(-2.0f*fabsf(x));
  float t = (1.0f - e)/(1.0f + e);
  return copysignf(t, x);
}

extern "C" __global__ void __launch_bounds__(NTHR, 2)
qlstm_kern(const int* __restrict__ x, const float* __restrict__ emb,
           const float* __restrict__ W0, const float* __restrict__ b0v, const float* __restrict__ bb0v,
           const float* __restrict__ W1, const float* __restrict__ b1v, const float* __restrict__ bb1v,
           const float* __restrict__ fcw, const float* __restrict__ fcb,
           float* __restrict__ out, float* __restrict__ ws)
{
  extern __shared__ float smem[];
  const int t = threadIdx.x;
  const int bid = blockIdx.x;
  const bool isL0 = (bid < 128);
  const int gbase = (isL0 ? bid : (bid - 128)) << 2;
  const int K = isL0 ? K0z : K1z;
  const int wsz = K*4 + 4;              // per-gatecol W stride in LDS (pad 4 words)
  float* Wl = smem + 2*KC*APAD;         // persistent W tile

  const int lane = t & 63;
  const int wv = t >> 6;
  const int b = (wv << 4) | (lane & 15);   // batch row 0..127
  const int gq = lane >> 4;                // 0..3 local gate-col
  const int gcol = gbase + gq;             // 0..511 hidden index

  float* hs  = ws;            // h0T: 2 bufs of [Hz][Bz]
  float* h1s = ws + 2*HB;     // h1T: 2 bufs
  int* flags = (int*)(ws + 4*HB);

  // zero h state (poison 0xAA otherwise)
  for (int i = bid*NTHR + t; i < 4*HB; i += NBLK*NTHR) ws[i] = 0.0f;

  // load W tile into LDS once: Wl[g2][k][gate], interleaved for b128 reads
  {
    const float* Wsrc = isL0 ? W0 : W1;
    for (int g2 = 0; g2 < 4; ++g2)
      for (int gate = 0; gate < 4; ++gate){
        const float* src = Wsrc + (size_t)(gate*Hz + gbase + g2)*K;
        float* dst = Wl + g2*wsz + gate;
        for (int k = t; k < K; k += NTHR) dst[k*4] = src[k];
      }
  }

  const float* bsrc  = isL0 ? b0v  : b1v;
  const float* bbsrc = isL0 ? bb0v : bb1v;
  const float bias0 = bsrc[0*Hz+gcol] + bbsrc[0*Hz+gcol];
  const float bias1 = bsrc[1*Hz+gcol] + bbsrc[1*Hz+gcol];
  const float bias2 = bsrc[2*Hz+gcol] + bbsrc[2*Hz+gcol];
  const float bias3 = bsrc[3*Hz+gcol] + bbsrc[3*Hz+gcol];

  float creg = 0.0f;   // cell state lives in a register forever

  auto gridbar = [&](int epoch){
    __syncthreads();
    if (t == 0){
      __threadfence();  // release: drain + L2 writeback (cross-XCD visibility)
      __hip_atomic_store(&flags[bid], epoch, __ATOMIC_RELEASE, __HIP_MEMORY_SCOPE_AGENT);
    }
    if (t < NBLK){
      // poison 0xAAAAAAAA is negative as int -> never counts as arrived
      while (__hip_atomic_load(&flags[t], __ATOMIC_RELAXED, __HIP_MEMORY_SCOPE_AGENT) < epoch)
        __builtin_amdgcn_s_sleep(4);
    }
    if (t == 0) __threadfence();  // acquire: invalidate L1/L2 before reading fresh h
    __syncthreads();
  };

  gridbar(1);

  const int nc = K / KC;

  for (int p = 0; p <= Sz; ++p){
    const int rb = (p + 1) & 1;
    const int wb = p & 1;
    const bool active = isL0 ? (p < Sz) : (p >= 1);
    if (active){
      const float* hr0 = hs  + rb*HB;
      const float* hr1 = h1s + rb*HB;
      int rows[4];
      if (isL0){
        #pragma unroll
        for (int m = 0; m < 4; ++m)
          rows[m] = x[((t + m*NTHR) >> 4)*Sz + p];
      }
      float4 v[4];
      float acc0 = 0.f, acc1 = 0.f, acc2 = 0.f, acc3 = 0.f;

      // issue global loads for chunk c into regs
      auto ld = [&](int c){
        const int k0 = c*KC;
        if (isL0 && k0 < Ez){
          #pragma unroll
          for (int m = 0; m < 4; ++m){
            const int f = t + m*NTHR;
            const int kq = f & 15;
            v[m] = *(const float4*)(emb + (size_t)rows[m]*Ez + k0 + (kq<<2));
          }
        } else {
          #pragma unroll
          for (int m = 0; m < 4; ++m){
            const int f = t + m*NTHR;
            const int r = f >> 5, c4 = f & 31;
            const int kg = k0 + r;
            const float* src;
            if (isL0) src = hr0 + (kg - Ez)*Bz;
            else      src = (kg < Hz) ? (hr0 + kg*Bz) : (hr1 + (kg - Hz)*Bz);
            v[m] = *(const float4*)(src + (c4<<2));
          }
        }
      };
      // write regs into LDS A-buffer [kk][b] (transpose for gather chunks)
      auto wr = [&](int c){
        float* Ab = smem + (c & 1)*(KC*APAD);
        const int k0 = c*KC;
        if (isL0 && k0 < Ez){
          #pragma unroll
          for (int m = 0; m < 4; ++m){
            const int f = t + m*NTHR;
            const int gb = f >> 4, kq = f & 15;
            float* d = Ab + gb;
            d[(4*kq+0)*APAD] = v[m].x;
            d[(4*kq+1)*APAD] = v[m].y;
            d[(4*kq+2)*APAD] = v[m].z;
            d[(4*kq+3)*APAD] = v[m].w;
          }
        } else {
          #pragma unroll
          for (int m = 0; m < 4; ++m){
            const int f = t + m*NTHR;
            const int r = f >> 5, c4 = f & 31;
            *(float4*)(Ab + r*APAD + (c4<<2)) = v[m];
          }
        }
      };
      auto cmp = [&](int c){
        const float* Ab = smem + (c & 1)*(KC*APAD) + b;
        const float* Wg = Wl + gq*wsz + c*KC*4;
        #pragma unroll
        for (int q = 0; q < 16; ++q){
          const float a0 = Ab[(4*q+0)*APAD];
          const float a1 = Ab[(4*q+1)*APAD];
          const float a2 = Ab[(4*q+2)*APAD];
          const float a3 = Ab[(4*q+3)*APAD];
          const float4 w0 = *(const float4*)(Wg + (4*q+0)*4);
          const float4 w1 = *(const float4*)(Wg + (4*q+1)*4);
          const float4 w2 = *(const float4*)(Wg + (4*q+2)*4);
          const float4 w3 = *(const float4*)(Wg + (4*q+3)*4);
          acc0 += a0*w0.x; acc1 += a0*w0.y; acc2 += a0*w0.z; acc3 += a0*w0.w;
          acc0 += a1*w1.x; acc1 += a1*w1.y; acc2 += a1*w1.z; acc3 += a1*w1.w;
          acc0 += a2*w2.x; acc1 += a2*w2.y; acc2 += a2*w2.z; acc3 += a2*w2.w;
          acc0 += a3*w3.x; acc1 += a3*w3.y; acc2 += a3*w3.z; acc3 += a3*w3.w;
        }
      };

      ld(0); wr(0); ld(1);          // prologue: double-buffered, loads 2 ahead
      for (int c = 0; c < nc; ++c){
        __syncthreads();
        if (c + 1 < nc) wr(c + 1);
        if (c + 2 < nc) ld(c + 2);
        cmp(c);
      }

      const float zf = acc0 + bias0;
      const float zi = acc1 + bias1;
      const float zc = acc2 + bias2;
      const float zo = acc3 + bias3;
      const float fg = sigm_(zf), ig = sigm_(zi), cg = tanh_(zc), og = sigm_(zo);
      creg = fg*creg + ig*cg;
      const float hval = og * tanh_(creg);
      float* hdst = (isL0 ? hs : h1s) + wb*HB;
      hdst[gcol*Bz + b] = hval;     // coalesced transposed store
    }
    gridbar(p + 2);
  }

  // final FC: out[b][o] = h1 . fc_w[o] + fc_b[o]; h1 final is in buf 0 (Sz even)
  if (bid == 0 && t < 2*Bz){
    const int ob = t >> 1, oo = t & 1;
    const float* hf = h1s;
    float a = fcb[oo];
    #pragma unroll 8
    for (int h = 0; h < Hz; ++h)
      a += hf[h*Bz + ob] * fcw[oo*Hz + h];
    out[ob*2 + oo] = a;
  }
}

extern "C" void kernel_launch(void* const* d_in, const int* in_sizes, int n_in,
                              void* d_out, int out_size, void* d_ws, size_t ws_size,
                              hipStream_t stream) {
  (void)in_sizes; (void)n_in; (void)out_size; (void)ws_size;
  const int*   x   = (const int*)d_in[0];
  const float* emb = (const float*)d_in[1];
  const float* W0  = (const float*)d_in[2];
  const float* b0  = (const float*)d_in[3];
  const float* bb0 = (const float*)d_in[4];
  const float* W1  = (const float*)d_in[5];
  const float* b1  = (const float*)d_in[6];
  const float* bb1 = (const float*)d_in[7];
  const float* fcw = (const float*)d_in[8];
  const float* fcb = (const float*)d_in[9];
  float* out = (float*)d_out;
  float* ws  = (float*)d_ws;

  const size_t shmem = (size_t)(2*KC*APAD + 4*(K1z*4 + 4)) * sizeof(float); // 133184 B
  hipFuncSetAttribute((const void*)qlstm_kern,
                      hipFuncAttributeMaxDynamicSharedMemorySize, (int)shmem);

  void* args[] = { (void*)&x, (void*)&emb, (void*)&W0, (void*)&b0, (void*)&bb0,
                   (void*)&W1, (void*)&b1, (void*)&bb1, (void*)&fcw, (void*)&fcb,
                   (void*)&out, (void*)&ws };
  hipLaunchCooperativeKernel((const void*)qlstm_kern, dim3(NBLK), dim3(NTHR),
                             args, (unsigned)shmem, stream);
}

// Round 2
// 72272.522 us; speedup vs baseline: 1.0034x; 1.0034x over previous
//
#include <hip/hip_runtime.h>
#include <math.h>

#define NBLK 256
#define NTHR 512
#define Bz 128
#define Sz 1024
#define Ez 256
#define Hz 512
#define K0z 768
#define K1z 1024
#define KC 64
#define APAD 132
#define HB (Hz*Bz)

__device__ __forceinline__ float sigm_(float x){ return 1.0f/(1.0f + __expf(-x)); }
__device__ __forceinline__ float tanh_(float x){
  float e = __expf(-2.0f*fabsf(x));
  float t = (1.0f - e)/(1.0f + e);
  return copysignf(t, x);
}

// L3-coherent (cross-XCD) flag ops: explicit sc0 sc1 so they can never hit a
// stale per-XCD L2 line. Self-draining; only used on the slow barrier path.
__device__ __forceinline__ void st_flag(int* p, int v){
  asm volatile("global_store_dword %0, %1, off sc0 sc1\n\ts_waitcnt vmcnt(0)"
               :: "v"(p), "v"(v) : "memory");
}
__device__ __forceinline__ int ld_flag(const int* p){
  int v;
  asm volatile("global_load_dword %0, %1, off sc0 sc1\n\ts_waitcnt vmcnt(0)"
               : "=v"(v) : "v"(p) : "memory");
  return v;
}

// h transport: relaxed agent-scope atomics lower to global_load/store_dword
// with sc1 on gfx94x/gfx950 (bypass L2 -> Infinity Cache = agent coherence
// point). Compiler-scheduled => stays pipelined, unlike self-waiting asm.
__device__ __forceinline__ float ldh(const float* p){
  return __hip_atomic_load(p, __ATOMIC_RELAXED, __HIP_MEMORY_SCOPE_AGENT);
}
__device__ __forceinline__ void sth(float* p, float v){
  __hip_atomic_store(p, v, __ATOMIC_RELAXED, __HIP_MEMORY_SCOPE_AGENT);
}

extern "C" __global__ void __launch_bounds__(NTHR, 2)
qlstm_kern(const int* __restrict__ x, const float* __restrict__ emb,
           const float* __restrict__ W0, const float* __restrict__ b0v, const float* __restrict__ bb0v,
           const float* __restrict__ W1, const float* __restrict__ b1v, const float* __restrict__ bb1v,
           const float* __restrict__ fcw, const float* __restrict__ fcb,
           float* __restrict__ out, float* __restrict__ ws)
{
  extern __shared__ float smem[];
  const int t = threadIdx.x;
  const int bid = blockIdx.x;
  const bool isL0 = (bid < 128);
  const int gbase = (isL0 ? bid : (bid - 128)) << 2;
  const int K = isL0 ? K0z : K1z;
  const int wsz = K*4 + 4;              // per-gatecol W stride in LDS (pad 4 words)
  float* Wl = smem + 2*KC*APAD;         // persistent W tile

  const int lane = t & 63;
  const int wv = t >> 6;
  const int b = (wv << 4) | (lane & 15);   // batch row 0..127
  const int gq = lane >> 4;                // 0..3 local gate-col
  const int gcol = gbase + gq;             // 0..511 hidden index

  float* hs  = ws;            // h0T: 2 bufs of [Hz][Bz]
  float* h1s = ws + 2*HB;     // h1T: 2 bufs
  int* flags = (int*)(ws + 4*HB);

  // zero h state through the coherent path (plain stores would sit dirty in
  // local L2 and be invisible to sc1 readers)
  for (int i = bid*NTHR + t; i < 4*HB; i += NBLK*NTHR) sth(&ws[i], 0.0f);

  // load W tile into LDS once: Wl[g2][k][gate], interleaved for b128 reads
  {
    const float* Wsrc = isL0 ? W0 : W1;
    for (int g2 = 0; g2 < 4; ++g2)
      for (int gate = 0; gate < 4; ++gate){
        const float* src = Wsrc + (size_t)(gate*Hz + gbase + g2)*K;
        float* dst = Wl + g2*wsz + gate;
        for (int k = t; k < K; k += NTHR) dst[k*4] = src[k];
      }
  }

  const float* bsrc  = isL0 ? b0v  : b1v;
  const float* bbsrc = isL0 ? bb0v : bb1v;
  const float bias0 = bsrc[0*Hz+gcol] + bbsrc[0*Hz+gcol];
  const float bias1 = bsrc[1*Hz+gcol] + bbsrc[1*Hz+gcol];
  const float bias2 = bsrc[2*Hz+gcol] + bbsrc[2*Hz+gcol];
  const float bias3 = bsrc[3*Hz+gcol] + bbsrc[3*Hz+gcol];

  float creg = 0.0f;   // cell state lives in a register forever

  // Fence-free grid barrier: no buffer_inv / buffer_wbl2, so L2 stays hot
  // (W/emb/x are read-only; all cross-XCD data moves through sc1 accesses).
  // __syncthreads drains each wave's vmcnt before s_barrier, so every h store
  // has reached L3 before thread 0 publishes the flag.
  auto gridbar = [&](int epoch){
    __syncthreads();
    if (t == 0){
      __builtin_amdgcn_s_waitcnt(0x0F70);  // vmcnt(0) belt-and-braces
      st_flag(&flags[bid], epoch);
    }
    if (t < NBLK){
      // poison 0xAAAAAAAA is negative as int -> never counts as arrived
      while (ld_flag(&flags[t]) < epoch) __builtin_amdgcn_s_sleep(4);
    }
    __syncthreads();
  };

  gridbar(1);

  const int nc = K / KC;

  for (int p = 0; p <= Sz; ++p){
    const int rb = (p + 1) & 1;
    const int wb = p & 1;
    const bool active = isL0 ? (p < Sz) : (p >= 1);
    if (active){
      const float* hr0 = hs  + rb*HB;
      const float* hr1 = h1s + rb*HB;
      int rows[4];
      if (isL0){
        #pragma unroll
        for (int m = 0; m < 4; ++m)
          rows[m] = x[((t + m*NTHR) >> 4)*Sz + p];
      }
      float4 v[4];
      float acc0 = 0.f, acc1 = 0.f, acc2 = 0.f, acc3 = 0.f;

      // issue global loads for chunk c into regs
      auto ld = [&](int c){
        const int k0 = c*KC;
        if (isL0 && k0 < Ez){
          #pragma unroll
          for (int m = 0; m < 4; ++m){
            const int f = t + m*NTHR;
            const int kq = f & 15;
            v[m] = *(const float4*)(emb + (size_t)rows[m]*Ez + k0 + (kq<<2));
          }
        } else {
          #pragma unroll
          for (int m = 0; m < 4; ++m){
            const int f = t + m*NTHR;
            const int r = f >> 5, c4 = f & 31;
            const int kg = k0 + r;
            const float* src;
            if (isL0) src = hr0 + (kg - Ez)*Bz;
            else      src = (kg < Hz) ? (hr0 + kg*Bz) : (hr1 + (kg - Hz)*Bz);
            const float* q = src + (c4<<2);
            v[m].x = ldh(q+0);
            v[m].y = ldh(q+1);
            v[m].z = ldh(q+2);
            v[m].w = ldh(q+3);
          }
        }
      };
      // write regs into LDS A-buffer [kk][b] (transpose for gather chunks)
      auto wr = [&](int c){
        float* Ab = smem + (c & 1)*(KC*APAD);
        const int k0 = c*KC;
        if (isL0 && k0 < Ez){
          #pragma unroll
          for (int m = 0; m < 4; ++m){
            const int f = t + m*NTHR;
            const int gb = f >> 4, kq = f & 15;
            float* d = Ab + gb;
            d[(4*kq+0)*APAD] = v[m].x;
            d[(4*kq+1)*APAD] = v[m].y;
            d[(4*kq+2)*APAD] = v[m].z;
            d[(4*kq+3)*APAD] = v[m].w;
          }
        } else {
          #pragma unroll
          for (int m = 0; m < 4; ++m){
            const int f = t + m*NTHR;
            const int r = f >> 5, c4 = f & 31;
            *(float4*)(Ab + r*APAD + (c4<<2)) = v[m];
          }
        }
      };
      auto cmp = [&](int c){
        const float* Ab = smem + (c & 1)*(KC*APAD) + b;
        const float* Wg = Wl + gq*wsz + c*KC*4;
        #pragma unroll
        for (int q = 0; q < 16; ++q){
          const float a0 = Ab[(4*q+0)*APAD];
          const float a1 = Ab[(4*q+1)*APAD];
          const float a2 = Ab[(4*q+2)*APAD];
          const float a3 = Ab[(4*q+3)*APAD];
          const float4 w0 = *(const float4*)(Wg + (4*q+0)*4);
          const float4 w1 = *(const float4*)(Wg + (4*q+1)*4);
          const float4 w2 = *(const float4*)(Wg + (4*q+2)*4);
          const float4 w3 = *(const float4*)(Wg + (4*q+3)*4);
          acc0 += a0*w0.x; acc1 += a0*w0.y; acc2 += a0*w0.z; acc3 += a0*w0.w;
          acc0 += a1*w1.x; acc1 += a1*w1.y; acc2 += a1*w1.z; acc3 += a1*w1.w;
          acc0 += a2*w2.x; acc1 += a2*w2.y; acc2 += a2*w2.z; acc3 += a2*w2.w;
          acc0 += a3*w3.x; acc1 += a3*w3.y; acc2 += a3*w3.z; acc3 += a3*w3.w;
        }
      };

      ld(0); wr(0); ld(1);          // prologue: double-buffered, loads 2 ahead
      for (int c = 0; c < nc; ++c){
        __syncthreads();
        if (c + 1 < nc) wr(c + 1);
        if (c + 2 < nc) ld(c + 2);
        cmp(c);
      }

      const float zf = acc0 + bias0;
      const float zi = acc1 + bias1;
      const float zc = acc2 + bias2;
      const float zo = acc3 + bias3;
      const float fg = sigm_(zf), ig = sigm_(zi), cg = tanh_(zc), og = sigm_(zo);
      creg = fg*creg + ig*cg;
      const float hval = og * tanh_(creg);
      float* hdst = (isL0 ? hs : h1s) + wb*HB;
      sth(&hdst[gcol*Bz + b], hval);   // coherent transposed store
    }
    gridbar(p + 2);
  }

  // final FC: out[b][o] = h1 . fc_w[o] + fc_b[o]; h1 final is in buf 0 (Sz even)
  if (bid == 0 && t < 2*Bz){
    const int ob = t >> 1, oo = t & 1;
    const float* hf = h1s;
    float a = fcb[oo];
    #pragma unroll 8
    for (int h = 0; h < Hz; ++h)
      a += ldh(&hf[h*Bz + ob]) * fcw[oo*Hz + h];
    out[ob*2 + oo] = a;
  }
}

extern "C" void kernel_launch(void* const* d_in, const int* in_sizes, int n_in,
                              void* d_out, int out_size, void* d_ws, size_t ws_size,
                              hipStream_t stream) {
  (void)in_sizes; (void)n_in; (void)out_size; (void)ws_size;
  const int*   x   = (const int*)d_in[0];
  const float* emb = (const float*)d_in[1];
  const float* W0  = (const float*)d_in[2];
  const float* b0  = (const float*)d_in[3];
  const float* bb0 = (const float*)d_in[4];
  const float* W1  = (const float*)d_in[5];
  const float* b1  = (const float*)d_in[6];
  const float* bb1 = (const float*)d_in[7];
  const float* fcw = (const float*)d_in[8];
  const float* fcb = (const float*)d_in[9];
  float* out = (float*)d_out;
  float* ws  = (float*)d_ws;

  const size_t shmem = (size_t)(2*KC*APAD + 4*(K1z*4 + 4)) * sizeof(float); // 133184 B
  hipFuncSetAttribute((const void*)qlstm_kern,
                      hipFuncAttributeMaxDynamicSharedMemorySize, (int)shmem);

  void* args[] = { (void*)&x, (void*)&emb, (void*)&W0, (void*)&b0, (void*)&bb0,
                   (void*)&W1, (void*)&b1, (void*)&bb1, (void*)&fcw, (void*)&fcb,
                   (void*)&out, (void*)&ws };
  hipLaunchCooperativeKernel((const void*)qlstm_kern, dim3(NBLK), dim3(NTHR),
                             args, (unsigned)shmem, stream);
}

// Round 3
// 16264.729 us; speedup vs baseline: 4.4588x; 4.4435x over previous
//
#include <hip/hip_runtime.h>
#include <math.h>

#define NBLK 256
#define NTHR 512
#define Bz 128
#define Sz 1024
#define Hz 512
#define HB (Hz*Bz)

typedef float        f32x4 __attribute__((ext_vector_type(4)));
typedef short        s16x8 __attribute__((ext_vector_type(8)));
typedef unsigned int u32x4 __attribute__((ext_vector_type(4)));

__device__ __forceinline__ float sigm_(float x){ return 1.0f/(1.0f + __expf(-x)); }
__device__ __forceinline__ float tanh_(float x){
  float e = __expf(-2.0f*fabsf(x));
  float t2 = (1.0f - e)/(1.0f + e);
  return copysignf(t2, x);
}
__device__ __forceinline__ unsigned f2bf(float x){           // RNE f32->bf16 bits
  unsigned u = __float_as_uint(x);
  return (u + 0x7fffu + ((u>>16)&1u)) >> 16;
}
__device__ __forceinline__ float bf2f(unsigned h){ return __uint_as_float(h<<16); }
__device__ __forceinline__ unsigned packh(float x){          // hi | lo<<16 (x == bf2f(hi)+bf2f(lo) to ~2^-17)
  unsigned hi = f2bf(x);
  unsigned lo = f2bf(x - bf2f(hi));
  return hi | (lo<<16);
}

// ---- coherence primitives (empirically validated in R2) ----
__device__ __forceinline__ void st_flag(int* p, int v){
  asm volatile("global_store_dword %0, %1, off sc0 sc1\n\ts_waitcnt vmcnt(0)"
               :: "v"(p), "v"(v) : "memory");
}
__device__ __forceinline__ int ld_flag(const int* p){
  int v;
  asm volatile("global_load_dword %0, %1, off sc0 sc1\n\ts_waitcnt vmcnt(0)"
               : "=v"(v) : "v"(p) : "memory");
  return v;
}
__device__ __forceinline__ void sth_u(unsigned* p, unsigned v){
  __hip_atomic_store(p, v, __ATOMIC_RELAXED, __HIP_MEMORY_SCOPE_AGENT);
}
__device__ __forceinline__ unsigned ldh_u(const unsigned* p){
  return __hip_atomic_load(p, __ATOMIC_RELAXED, __HIP_MEMORY_SCOPE_AGENT);
}

// ---- counted async loads: NO self-wait; paired with manual s_waitcnt vmcnt(N) ----
__device__ __forceinline__ unsigned ld_h1(const unsigned* p){   // L3-coherent h read
  unsigned r;
  asm volatile("global_load_dword %0, %1, off sc0 sc1" : "=v"(r) : "v"(p) : "memory");
  return r;
}
__device__ __forceinline__ void ld_e4(u32x4& d, const float* p){ // cached emb read (counted)
  asm volatile("global_load_dwordx4 %0, %1, off" : "=v"(d) : "v"(p) : "memory");
}
__device__ __forceinline__ void wait_vm(int n){   // n is block-uniform
  if (n == 0)      asm volatile("s_waitcnt vmcnt(0)"  ::: "memory");
  else if (n == 4) asm volatile("s_waitcnt vmcnt(4)"  ::: "memory");
  else             asm volatile("s_waitcnt vmcnt(16)" ::: "memory");
}
// block barrier WITHOUT vmcnt drain (keeps prefetch loads in flight)
__device__ __forceinline__ void barrier_fast(){
  asm volatile("s_waitcnt lgkmcnt(0)\n\ts_barrier" ::: "memory");
}

extern "C" __global__ void __launch_bounds__(NTHR, 2)
qlstm_kern(const int* __restrict__ x, const float* __restrict__ emb,
           const float* __restrict__ W0, const float* __restrict__ b0v, const float* __restrict__ bb0v,
           const float* __restrict__ W1, const float* __restrict__ b1v, const float* __restrict__ bb1v,
           const float* __restrict__ fcw, const float* __restrict__ fcb,
           float* __restrict__ out, float* __restrict__ ws)
{
  extern __shared__ char sm[];
  // LDS map (bytes): [0,65536) A double-buffer: buf*32768 + plane(hi/lo)*16384
  //                  [65536,98304) W_hi frags ; [98304,131072) W_lo frags
  //                  zbuf (8KB) aliases offset 0 after the K-loop.
  const int t   = threadIdx.x;
  const int bid = blockIdx.x;
  const bool isL0 = (bid < 128);
  const int gbase = (isL0 ? bid : bid - 128) << 2;   // 4 hidden cols per block
  const int K  = isL0 ? 768 : 1024;
  const int KS = K >> 5;       // 16x16x32 k-steps
  const int NCh = K >> 6;      // 64-k chunks (even: 12 / 16)

  const int lane = t & 63;
  const int mt   = t >> 6;           // wave = M-tile (16 batch rows)
  const int m16  = lane & 15;
  const int q4   = lane >> 4;
  const int aoff = (q4*128 + mt*16 + m16) * 16;  // A-frag byte offset within (buf,plane,kc2)
  const int boff = lane * 16;                    // B-frag byte offset within kc step

  const int b_s = t & 127;           // stager: batch column
  const int g0  = (t >> 7) * 2;      // stager: first of 2 k-groups (8 k each)

  const int b_c = t >> 2;            // cell thread: batch
  const int hl  = t & 3;             // cell thread: local hidden col

  unsigned* h0s = (unsigned*)ws;           // 2 bufs of [Hz][Bz] packed bf16-pairs
  unsigned* h1s = h0s + 2*HB;
  int* flags = (int*)(h0s + 4*HB);

  // zero h state through the coherent path
  for (int i = bid*NTHR + t; i < 4*HB; i += NBLK*NTHR) sth_u(&h0s[i], 0u);

  // ---- one-time W -> LDS B-fragment layout (hi/lo bf16 planes) ----
  {
    const float* Wsrc = isL0 ? W0 : W1;
    const int gtot = KS * 64;                 // groups: g = kc*64 + q*16 + n
    for (int g = t; g < gtot; g += NTHR){
      const int kc = g >> 6, q = (g >> 4) & 3, n = g & 15;
      const int zrow = (n & 3)*Hz + gbase + (n >> 2);   // gate = n&3, hid = n>>2
      const float* src = Wsrc + (size_t)zrow*K + kc*32 + q*8;
      const float4 e0 = *(const float4*)(src);
      const float4 e1 = *(const float4*)(src + 4);
      float ev[8] = {e0.x,e0.y,e0.z,e0.w,e1.x,e1.y,e1.z,e1.w};
      unsigned hiw[4], low[4];
      #pragma unroll
      for (int k2 = 0; k2 < 4; ++k2){
        unsigned ha = f2bf(ev[2*k2]),   hb = f2bf(ev[2*k2+1]);
        unsigned la = f2bf(ev[2*k2]   - bf2f(ha));
        unsigned lb = f2bf(ev[2*k2+1] - bf2f(hb));
        hiw[k2] = ha | (hb << 16);
        low[k2] = la | (lb << 16);
      }
      *(u32x4*)(sm + 65536 + g*16) = (u32x4){hiw[0],hiw[1],hiw[2],hiw[3]};
      *(u32x4*)(sm + 98304 + g*16) = (u32x4){low[0],low[1],low[2],low[3]};
    }
  }

  // bias per cell thread (4 gates of hidden col gbase+hl)
  const float* bsrc  = isL0 ? b0v  : b1v;
  const float* bbsrc = isL0 ? bb0v : bb1v;
  float bias[4];
  #pragma unroll
  for (int g = 0; g < 4; ++g)
    bias[g] = bsrc[g*Hz + gbase + hl] + bbsrc[g*Hz + gbase + hl];

  float creg = 0.0f;
  __syncthreads();

  auto gridbar = [&](int epoch){
    __syncthreads();                       // full drain incl. vmcnt (h stores reach L3)
    if (t == 0){
      __builtin_amdgcn_s_waitcnt(0x0F70);  // vmcnt(0) belt-and-braces
      st_flag(&flags[bid], epoch);
    }
    if (t < NBLK){
      while (ld_flag(&flags[t]) < epoch) __builtin_amdgcn_s_sleep(4);
    }
    __syncthreads();
  };

  gridbar(1);

  for (int p = 0; p <= Sz; ++p){
    const int rb = (p + 1) & 1;
    const int wb = p & 1;
    const bool active = isL0 ? (p < Sz) : (p >= 1);
    if (active){
      const unsigned* h0r = h0s + rb*HB;
      const unsigned* h1r = h1s + rb*HB;
      const float* embrow = emb;
      if (isL0){
        int row = x[b_s*Sz + p];
        embrow = emb + (size_t)row * 256;   // use of row forces its wait here
      }
      asm volatile("s_waitcnt vmcnt(0)" ::: "memory");   // clean counter baseline

      u32x4 va[4], vb[4];
      f32x4 acc = {0.f, 0.f, 0.f, 0.f};

      // per-thread chunk load: 2 groups of 8 k for batch b_s
      auto LD = [&](int c, u32x4 (&v)[4]){
        const int k0 = c * 64;
        if (isL0 && k0 < 256){
          #pragma unroll
          for (int gi = 0; gi < 2; ++gi){
            const int kg = k0 + (g0 + gi)*8;
            ld_e4(v[gi*2+0], embrow + kg);
            ld_e4(v[gi*2+1], embrow + kg + 4);
          }
        } else {
          #pragma unroll
          for (int gi = 0; gi < 2; ++gi){
            const int kg = k0 + (g0 + gi)*8;
            const unsigned* src;
            if (isL0)          src = h0r + (kg - 256)*Bz + b_s;
            else if (kg < Hz)  src = h0r + kg*Bz + b_s;
            else               src = h1r + (kg - Hz)*Bz + b_s;
            #pragma unroll
            for (int j = 0; j < 8; ++j){
              unsigned r = ld_h1(src + j*Bz);
              v[gi*2 + (j>>2)][j & 3] = r;
            }
          }
        }
      };

      auto WR = [&](int c, u32x4 (&v)[4]){
        const int buf = c & 1;
        char* Ah = sm + buf*32768;
        char* Al = Ah + 16384;
        const int k0 = c * 64;
        #pragma unroll
        for (int gi = 0; gi < 2; ++gi){
          unsigned s[8];
          #pragma unroll
          for (int j = 0; j < 8; ++j) s[j] = v[gi*2 + (j>>2)][j & 3];
          unsigned hiw[4], low[4];
          if (isL0 && k0 < 256){
            #pragma unroll
            for (int k2 = 0; k2 < 4; ++k2){
              float ea = __uint_as_float(s[2*k2]), eb = __uint_as_float(s[2*k2+1]);
              unsigned ha = f2bf(ea), hb = f2bf(eb);
              unsigned la = f2bf(ea - bf2f(ha)), lb = f2bf(eb - bf2f(hb));
              hiw[k2] = ha | (hb << 16);
              low[k2] = la | (lb << 16);
            }
          } else {
            #pragma unroll
            for (int k2 = 0; k2 < 4; ++k2){
              hiw[k2] = (s[2*k2] & 0xffffu) | (s[2*k2+1] << 16);
              low[k2] = (s[2*k2] >> 16)     | (s[2*k2+1] & 0xffff0000u);
            }
          }
          const int off = ((g0 + gi)*128 + b_s) * 16;
          *(u32x4*)(Ah + off) = (u32x4){hiw[0],hiw[1],hiw[2],hiw[3]};
          *(u32x4*)(Al + off) = (u32x4){low[0],low[1],low[2],low[3]};
        }
      };

      auto CMP = [&](int c){
        const int buf = c & 1;
        const char* Ab = sm + buf*32768 + aoff;
        const char* Wb = sm + 65536 + (c*2)*1024 + boff;
        #pragma unroll
        for (int k2 = 0; k2 < 2; ++k2){
          u32x4 ah = *(const u32x4*)(Ab + k2*8192);
          u32x4 al = *(const u32x4*)(Ab + 16384 + k2*8192);
          u32x4 bh = *(const u32x4*)(Wb + k2*1024);
          u32x4 bl = *(const u32x4*)(Wb + 32768 + k2*1024);
          s16x8 fah = __builtin_bit_cast(s16x8, ah);
          s16x8 fal = __builtin_bit_cast(s16x8, al);
          s16x8 fbh = __builtin_bit_cast(s16x8, bh);
          s16x8 fbl = __builtin_bit_cast(s16x8, bl);
          acc = __builtin_amdgcn_mfma_f32_16x16x32_bf16(fah, fbh, acc, 0, 0, 0);
          acc = __builtin_amdgcn_mfma_f32_16x16x32_bf16(fah, fbl, acc, 0, 0, 0);
          acc = __builtin_amdgcn_mfma_f32_16x16x32_bf16(fal, fbh, acc, 0, 0, 0);
        }
      };

      auto CNT = [&](int c)->int{
        if (c >= NCh) return 0;
        return (isL0 && c < 4) ? 4 : 16;
      };

      LD(0, va); LD(1, vb);
      for (int c = 0; c < NCh; c += 2){
        wait_vm(CNT(c+1));  WR(c, va);   if (c+2 < NCh) LD(c+2, va);
        barrier_fast(); CMP(c);   barrier_fast();
        wait_vm(CNT(c+2));  WR(c+1, vb); if (c+3 < NCh) LD(c+3, vb);
        barrier_fast(); CMP(c+1); barrier_fast();
      }

      // ---- epilogue: z -> LDS (alias buf0-hi region), cell update, h store ----
      {
        float* zb = (float*)sm;
        const int n_z = lane & 15;
        #pragma unroll
        for (int r = 0; r < 4; ++r){
          const int b_z = mt*16 + q4*4 + r;
          zb[b_z*16 + n_z] = acc[r];
        }
      }
      __syncthreads();
      {
        const f32x4 z = *(const f32x4*)((const float*)sm + t*4);  // gates f,i,c,o of (b_c, hl)
        const float fg = sigm_(z[0] + bias[0]);
        const float ig = sigm_(z[1] + bias[1]);
        const float cg = tanh_(z[2] + bias[2]);
        const float og = sigm_(z[3] + bias[3]);
        creg = fg*creg + ig*cg;
        const float hval = og * tanh_(creg);
        unsigned* hdst = (isL0 ? h0s : h1s) + wb*HB;
        sth_u(&hdst[(gbase + hl)*Bz + b_c], packh(hval));
      }
    }
    gridbar(p + 2);
  }

  // final FC: out[b][o] = h1 . fc_w[o] + fc_b[o]; final h1 in buf 0 (Sz even)
  if (bid == 0 && t < 2*Bz){
    const int ob = t >> 1, oo = t & 1;
    const unsigned* hf = h1s;
    float a = fcb[oo];
    #pragma unroll 8
    for (int h = 0; h < Hz; ++h){
      const unsigned pv = ldh_u(&hf[h*Bz + ob]);
      a += (bf2f(pv & 0xffffu) + bf2f(pv >> 16)) * fcw[oo*Hz + h];
    }
    out[ob*2 + oo] = a;
  }
}

extern "C" void kernel_launch(void* const* d_in, const int* in_sizes, int n_in,
                              void* d_out, int out_size, void* d_ws, size_t ws_size,
                              hipStream_t stream) {
  (void)in_sizes; (void)n_in; (void)out_size; (void)ws_size;
  const int*   x   = (const int*)d_in[0];
  const float* emb = (const float*)d_in[1];
  const float* W0  = (const float*)d_in[2];
  const float* b0  = (const float*)d_in[3];
  const float* bb0 = (const float*)d_in[4];
  const float* W1  = (const float*)d_in[5];
  const float* b1  = (const float*)d_in[6];
  const float* bb1 = (const float*)d_in[7];
  const float* fcw = (const float*)d_in[8];
  const float* fcb = (const float*)d_in[9];
  float* out = (float*)d_out;
  float* ws  = (float*)d_ws;

  const size_t shmem = 131072;   // 64KB A dbuf + 32KB W_hi + 32KB W_lo
  hipFuncSetAttribute((const void*)qlstm_kern,
                      hipFuncAttributeMaxDynamicSharedMemorySize, (int)shmem);

  void* args[] = { (void*)&x, (void*)&emb, (void*)&W0, (void*)&b0, (void*)&bb0,
                   (void*)&W1, (void*)&b1, (void*)&bb1, (void*)&fcw, (void*)&fcb,
                   (void*)&out, (void*)&ws };
  hipLaunchCooperativeKernel((const void*)qlstm_kern, dim3(NBLK), dim3(NTHR),
                             args, (unsigned)shmem, stream);
}